// Round 12
// baseline (349.160 us; speedup 1.0000x reference)
//
#include <hip/hip_runtime.h>
#include <hip/hip_bf16.h>
#include <stdint.h>

#define TT 1024
#define BB 32
#define DD 1024
#define MROWS (TT*BB)   // 32768
#define NCOLS (2*DD)    // 2048
#define KDIM  (DD)      // 1024
#define SS (BB*DD)      // 32768

typedef __attribute__((ext_vector_type(8))) short short8;
typedef __attribute__((ext_vector_type(16))) float f32x16;

__device__ __forceinline__ float bf2f(uint16_t u){
  union { uint32_t u; float f; } c; c.u = ((uint32_t)u) << 16; return c.f;
}
__device__ __forceinline__ uint16_t f2bf(float f){
  union { float f; uint32_t u; } c; c.f = f;
  uint32_t u = c.u;
  u += 0x7FFFu + ((u >> 16) & 1u);   // RNE
  return (uint16_t)(u >> 16);
}
__device__ __forceinline__ float tanh_fast(float x){
  return 1.f - 2.f/(1.f + __expf(2.f*x));
}
__device__ __forceinline__ float sigmoid_fast(float x){
  return __builtin_amdgcn_rcpf(1.f + __expf(-x));
}

// ---------------- convert x to bf16 ----------------
__global__ __launch_bounds__(256) void cvt_x_kernel(const float* __restrict__ x,
                                                    uint16_t* __restrict__ xb, int n4){
  int i = blockIdx.x * 256 + threadIdx.x;
  int stride = gridDim.x * 256;
  for (; i < n4; i += stride){
    float4 f = ((const float4*)x)[i];
    ushort4 o;
    o.x = f2bf(f.x); o.y = f2bf(f.y); o.z = f2bf(f.z); o.w = f2bf(f.w);
    ((ushort4*)xb)[i] = o;
  }
}

// ---------------- pack W to bf16, pair-interleaved ----------------
// wc row c: e = ((c>>5)<<4)|(c&15), s=(c>>4)&1; wc[c] = (s?Wx:Wa)[e]
// -> in each 32-row group: rows 0-15 = Wa[e0..e0+15], rows 16-31 = Wx[e0..e0+15]
__global__ __launch_bounds__(256) void cvt_w_kernel(const float* __restrict__ Wa,
                                                    const float* __restrict__ Wx,
                                                    uint16_t* __restrict__ wc){
  int i = blockIdx.x * 256 + threadIdx.x;   // float4 units
  const int c    = i >> 8;
  const int col4 = i & 255;
  const int e = ((c >> 5) << 4) | (c & 15);
  const int s = (c >> 4) & 1;
  const float* src = (s ? Wx : Wa) + (size_t)e*DD + col4*4;
  float4 f = *(const float4*)src;
  ushort4 o;
  o.x = f2bf(f.x); o.y = f2bf(f.y); o.z = f2bf(f.z); o.w = f2bf(f.w);
  ((ushort4*)wc)[i] = o;
}

// ---------------- dual GEMM, 256x256 tile, BK=32, 3-buffer, 32x32x16 MFMA ----------------
// r5 schedule (1 barrier/tile, counted vmcnt) with the bigger MFMA shape:
// 16 mfma_32x32x16 + 12 ds_read_b128 per wave per K32-tile (was 32 + 12).
// av[t*SS+b*DD+e]: low16 = a, high16 = tanh(v + bv)
__global__ __launch_bounds__(512, 2) void gemm_dual(const uint16_t* __restrict__ xb,
                                                    const uint16_t* __restrict__ wc,
                                                    const float* __restrict__ bv,
                                                    uint32_t* __restrict__ av){
  // 96 KiB: buffer r (r=0,1,2) at byte r*32768: A[256][32] @0, B[256][32] @16384
  __shared__ __align__(16) uint16_t lds[49152];
  char* ldsc = (char*)lds;

  const int tid  = threadIdx.x;        // 0..511
  const int lane = tid & 63;
  const int w    = tid >> 6;           // wave 0..7
  const int wm   = w >> 2;             // 0..1  (M half: 128 rows)
  const int wn   = w & 3;              // 0..3  (N quarter: 64 cols)
  const int fr32 = lane & 31;
  const int l5   = lane >> 5;          // 0..1

  // XCD-aware bijective swizzle: 1024 blocks, 8 XCDs
  const int bid = blockIdx.x;
  const int bsw = (bid & 7) * 128 + (bid >> 3);
  const int bm  = (bsw >> 3) << 8;     // row-tile * 256
  const int bn  = (bsw & 7) << 8;      // col-tile * 256

  f32x16 acc[4][2] = {};               // 4 m-subtiles x 2 n-subtiles of 32x32

  // staging: thread -> row tid>>2, phys 16B slot tid&3, logical slot = phys ^ ((row>>1)&3)
  const int lslot = (tid & 3) ^ ((tid >> 3) & 3);

  // unit u of K-tile kt -> buffer bufb: u0=A rows0-127, u1=A rows128-255,
  //                                     u2=B rows0-127, u3=B rows128-255
  #define STAGE_UNIT(kt, bufb, u) { \
    const uint16_t* s_ = ((u) < 2) ? xb : wc; \
    const int gb_ = ((u) < 2) ? bm : bn; \
    const int reg_ = ((u) < 2) ? 0 : 16384; \
    const int rb_ = ((u) & 1) * 128; \
    const uint16_t* g_ = s_ + (size_t)(gb_ + rb_ + (tid >> 2))*KDIM + (kt)*32 + lslot*8; \
    char* d_ = ldsc + (bufb) + reg_ + rb_*64 + w*1024; \
    __builtin_amdgcn_global_load_lds((const __attribute__((address_space(1))) void*)g_, \
                                     (__attribute__((address_space(3))) void*)d_, 16, 0, 0); \
  }

  // fragment reads (32x32x16): lane holds row fr32, k = l5*8 + kh*16 (8 bf16 = b128).
  // logical slot = kh*2 + l5; phys = slot ^ ((row>>1)&3); row>>1&3 = (fr32>>1)&3 here
  // (m/n subtile offsets are 32-aligned).
  const int sw2  = (fr32 >> 1) & 3;
  const int sA0  = (l5 ^ sw2) * 16;          // kh=0 slot byte-offset
  const int sA1  = ((2 | l5) ^ sw2) * 16;    // kh=1
  const int abase = (wm*128 + fr32)*64;      // + m*2048 + sA{kh}
  const int bbase = 16384 + (wn*64 + fr32)*64; // + n*2048 + sA{kh}

  // prologue: stage tiles 0 and 1
  STAGE_UNIT(0, 0, 0) STAGE_UNIT(0, 0, 1) STAGE_UNIT(0, 0, 2) STAGE_UNIT(0, 0, 3)
  STAGE_UNIT(1, 32768, 0) STAGE_UNIT(1, 32768, 1) STAGE_UNIT(1, 32768, 2) STAGE_UNIT(1, 32768, 3)
  asm volatile("s_waitcnt vmcnt(4)" ::: "memory");   // tile 0 landed; tile 1 in flight
  __builtin_amdgcn_s_barrier();

  int bR = 0;
  for (int t = 0; t < 32; ++t){
    const int bRb = bR * 32768;
    const int bW  = (bR == 0) ? 2 : (bR - 1);   // == (t+2)%3
    const int bWb = bW * 32768;

    short8 aF[4], bF[2], aG[4], bG[2];
    // kh = 0
    #pragma unroll
    for (int m = 0; m < 4; ++m)
      aF[m] = *(const short8*)(ldsc + bRb + abase + m*2048 + sA0);
    if (t < 30){ STAGE_UNIT(t+2, bWb, 0) STAGE_UNIT(t+2, bWb, 1) }
    #pragma unroll
    for (int n = 0; n < 2; ++n)
      bF[n] = *(const short8*)(ldsc + bRb + bbase + n*2048 + sA0);
    if (t < 30){ STAGE_UNIT(t+2, bWb, 2) STAGE_UNIT(t+2, bWb, 3) }
    #pragma unroll
    for (int m = 0; m < 4; ++m)
      #pragma unroll
      for (int n = 0; n < 2; ++n)
        acc[m][n] = __builtin_amdgcn_mfma_f32_32x32x16_bf16(aF[m], bF[n], acc[m][n], 0, 0, 0);

    // kh = 1
    #pragma unroll
    for (int m = 0; m < 4; ++m)
      aG[m] = *(const short8*)(ldsc + bRb + abase + m*2048 + sA1);
    #pragma unroll
    for (int n = 0; n < 2; ++n)
      bG[n] = *(const short8*)(ldsc + bRb + bbase + n*2048 + sA1);
    #pragma unroll
    for (int m = 0; m < 4; ++m)
      #pragma unroll
      for (int n = 0; n < 2; ++n)
        acc[m][n] = __builtin_amdgcn_mfma_f32_32x32x16_bf16(aG[m], bG[n], acc[m][n], 0, 0, 0);

    // tile boundary: tile t+1 landed (counted; t+2's 4 stay in flight), one barrier
    if (t < 30){
      asm volatile("s_waitcnt vmcnt(4)" ::: "memory");
      __builtin_amdgcn_s_barrier();
    } else if (t == 30){
      asm volatile("s_waitcnt vmcnt(0)" ::: "memory");
      __builtin_amdgcn_s_barrier();
    }

    bR = (bR == 2) ? 0 : (bR + 1);
  }
  #undef STAGE_UNIT

  // epilogue: 32x32 C/D map col=lane&31, row=(reg&3)+8*(reg>>2)+4*(lane>>5) [m74/m101].
  // wc interleave: cols 0-15 of each 32-group = a(e0..e0+15), cols 16-31 = v(same e).
  // shfl_xor(.,16) pairs (a,v) in-lane; lanes with (fr32&16)==0 pack + store u32.
  const bool isA = (fr32 & 16) == 0;
  const int e16 = fr32 & 15;
  #pragma unroll
  for (int ni = 0; ni < 2; ++ni){
    const int e = ((bn + wn*64 + ni*32) >> 1) + e16;
    const float bvn = bv[e];
    #pragma unroll
    for (int mi = 0; mi < 4; ++mi){
      #pragma unroll
      for (int r = 0; r < 16; ++r){
        const float own = acc[mi][ni][r];
        const float partner = __shfl_xor(own, 16, 64);
        if (isA){
          const int row = bm + wm*128 + mi*32 + (r & 3) + 8*(r >> 2) + 4*l5;
          const int tt = row >> 5, b = row & 31;
          const float vt = tanh_fast(partner + bvn);
          av[(size_t)tt*SS + (size_t)b*DD + e] = (uint32_t)f2bf(own) | ((uint32_t)f2bf(vt) << 16);
        }
      }
    }
  }
}

// ---------------- scan over t: one thread per (b,e), depth-32 prefetch ----------------
#define SCAN_STEP(u, tcur)                                        \
  {                                                               \
    const float a_ = bf2f((uint16_t)(u));                         \
    const float v_ = bf2f((uint16_t)((u) >> 16));                 \
    const float al_ = sigmoid_fast(a_ + da*h + ba);               \
    h = al_*(h - v_) + v_;                                        \
    const float sg_ = sigmoid_fast(h);                            \
    __builtin_nontemporal_store(h*h*sg_, &outs[(size_t)(tcur)*SS + idx]); \
    __builtin_nontemporal_store(h, &houts[(size_t)((tcur)+1)*SS + idx]);  \
  }

__global__ __launch_bounds__(64) void scan_kernel(const uint32_t* __restrict__ av,
                                                  const float* __restrict__ h0,
                                                  const float* __restrict__ d_alpha,
                                                  const float* __restrict__ b_alpha,
                                                  float* __restrict__ outs,
                                                  float* __restrict__ houts){
  const int idx = blockIdx.x * 64 + threadIdx.x;   // 0..32767 = b*D+e
  const int e = idx & (DD-1);
  const float da = d_alpha[e];
  const float ba = b_alpha[e];
  float h = h0[idx];
  __builtin_nontemporal_store(h, &houts[idx]);

  uint32_t bufA[32], bufB[32];
  #pragma unroll
  for (int j = 0; j < 32; ++j) bufA[j] = av[(size_t)j*SS + idx];

  for (int t0 = 0; t0 < TT; t0 += 64){
    #pragma unroll
    for (int j = 0; j < 32; ++j) bufB[j] = av[(size_t)(t0+32+j)*SS + idx];
    #pragma unroll
    for (int j = 0; j < 32; ++j) SCAN_STEP(bufA[j], t0 + j);
    if (t0 + 64 < TT){
      #pragma unroll
      for (int j = 0; j < 32; ++j) bufA[j] = av[(size_t)(t0+64+j)*SS + idx];
    }
    #pragma unroll
    for (int j = 0; j < 32; ++j) SCAN_STEP(bufB[j], t0 + 32 + j);
  }
}

extern "C" void kernel_launch(void* const* d_in, const int* in_sizes, int n_in,
                              void* d_out, int out_size, void* d_ws, size_t ws_size,
                              hipStream_t stream){
  const float* x  = (const float*)d_in[0];
  const float* h0 = (const float*)d_in[1];
  const float* Wa = (const float*)d_in[2];
  const float* da = (const float*)d_in[3];
  const float* ba = (const float*)d_in[4];
  const float* Wx = (const float*)d_in[5];
  const float* bv = (const float*)d_in[6];

  float* outs  = (float*)d_out;                       // [T,B,D]
  float* houts = outs + (size_t)TT*BB*DD;             // [T+1,B,D]

  // workspace: wc 4MB | xb 64MB | av 128MB
  uint8_t* ws = (uint8_t*)d_ws;
  uint16_t* wcb = (uint16_t*)ws;
  uint16_t* xb  = (uint16_t*)(ws + (size_t)NCOLS*KDIM*2);
  uint32_t* av  = (uint32_t*)(ws + (size_t)NCOLS*KDIM*2 + (size_t)MROWS*KDIM*2);

  hipLaunchKernelGGL(cvt_w_kernel, dim3(2048), dim3(256), 0, stream, Wa, Wx, wcb);
  hipLaunchKernelGGL(cvt_x_kernel, dim3(2048), dim3(256), 0, stream, x, xb, MROWS*KDIM/4);
  hipLaunchKernelGGL(gemm_dual, dim3((NCOLS/256)*(MROWS/256)), dim3(512), 0, stream,
                     xb, wcb, bv, av);
  hipLaunchKernelGGL(scan_kernel, dim3(SS/64), dim3(64), 0, stream,
                     av, h0, da, ba, outs, houts);
}

// Round 13
// 257.840 us; speedup vs baseline: 1.3542x; 1.3542x over previous
//
#include <hip/hip_runtime.h>
#include <hip/hip_bf16.h>
#include <stdint.h>

#define TT 1024
#define BB 32
#define DD 1024
#define MROWS (TT*BB)   // 32768
#define NCOLS (2*DD)    // 2048
#define KDIM  (DD)      // 1024
#define SS (BB*DD)      // 32768

typedef __attribute__((ext_vector_type(8))) short short8;
typedef __attribute__((ext_vector_type(4))) float f32x4;

__device__ __forceinline__ float bf2f(uint16_t u){
  union { uint32_t u; float f; } c; c.u = ((uint32_t)u) << 16; return c.f;
}
__device__ __forceinline__ uint16_t f2bf(float f){
  union { float f; uint32_t u; } c; c.f = f;
  uint32_t u = c.u;
  u += 0x7FFFu + ((u >> 16) & 1u);   // RNE
  return (uint16_t)(u >> 16);
}
__device__ __forceinline__ float tanh_fast(float x){
  return 1.f - 2.f/(1.f + __expf(2.f*x));
}
__device__ __forceinline__ float sigmoid_fast(float x){
  return __builtin_amdgcn_rcpf(1.f + __expf(-x));
}

// ---------------- fused convert: W (pair-interleaved) then x, one grid-stride kernel ----
// W part (i < n4w): wc row c: e = ((c>>5)<<4)|(c&15), s=(c>>4)&1; wc[c] = (s?Wx:Wa)[e]
// x part: straight f32->bf16.
__global__ __launch_bounds__(256) void cvt_all_kernel(const float* __restrict__ Wa,
                                                      const float* __restrict__ Wx,
                                                      uint16_t* __restrict__ wc,
                                                      const float* __restrict__ x,
                                                      uint16_t* __restrict__ xb){
  const int n4w = NCOLS*KDIM/4;             // 524288
  const int n4x = MROWS*KDIM/4;             // 8388608
  const int total = n4w + n4x;
  int i = blockIdx.x * 256 + threadIdx.x;
  const int stride = gridDim.x * 256;
  for (; i < total; i += stride){
    if (i < n4w){
      const int c    = i >> 8;
      const int col4 = i & 255;
      const int e = ((c >> 5) << 4) | (c & 15);
      const int s = (c >> 4) & 1;
      const float* src = (s ? Wx : Wa) + (size_t)e*DD + col4*4;
      float4 f = *(const float4*)src;
      ushort4 o;
      o.x = f2bf(f.x); o.y = f2bf(f.y); o.z = f2bf(f.z); o.w = f2bf(f.w);
      ((ushort4*)wc)[i] = o;
    } else {
      const int j = i - n4w;
      float4 f = ((const float4*)x)[j];
      ushort4 o;
      o.x = f2bf(f.x); o.y = f2bf(f.y); o.z = f2bf(f.z); o.w = f2bf(f.w);
      ((ushort4*)xb)[j] = o;
    }
  }
}

// ---------------- dual GEMM, 256x256 tile, BK=32, 3-buffer, 1 barrier/tile ----------------
// C[m][c] = sum_d x[m][d]*wc[c][d]; col pairs (even n -> a, odd n -> v);
// av[t*SS+b*DD+e]: low16 = a, high16 = tanh(v + bv)
__global__ __launch_bounds__(512, 2) void gemm_dual(const uint16_t* __restrict__ xb,
                                                    const uint16_t* __restrict__ wc,
                                                    const float* __restrict__ bv,
                                                    uint32_t* __restrict__ av){
  // 96 KiB: buffer r (r=0,1,2) at byte r*32768: A[256][32] then B[256][32] (+16384)
  __shared__ __align__(16) uint16_t lds[49152];
  char* ldsc = (char*)lds;

  const int tid  = threadIdx.x;        // 0..511
  const int lane = tid & 63;
  const int w    = tid >> 6;           // wave 0..7
  const int wm   = w >> 2;             // 0..1  (M half)
  const int wn   = w & 3;              // 0..3  (N quarter)
  const int fr   = lane & 15;
  const int fq   = lane >> 4;

  // XCD-aware bijective swizzle: 1024 blocks, 8 XCDs
  const int bid = blockIdx.x;
  const int bsw = (bid & 7) * 128 + (bid >> 3);
  const int bm  = (bsw >> 3) << 8;     // row-tile * 256
  const int bn  = (bsw & 7) << 8;      // col-tile * 256

  f32x4 acc[8][4] = {};

  // staging: thread -> row tid>>2 (0..127 per unit), phys 16B slot tid&3,
  // logical (global) slot = phys ^ ((row>>1)&3)  [measured 0-conflict swizzle]
  const int lslot = (tid & 3) ^ ((tid >> 3) & 3);

  // unit u of K-tile kt into buffer byte-offset bufb:
  //  u=0: A rows 0-127, u=1: A rows 128-255, u=2: B rows 0-127, u=3: B rows 128-255
  #define STAGE_UNIT(kt, bufb, u) { \
    const uint16_t* s_ = ((u) < 2) ? xb : wc; \
    const int gb_ = ((u) < 2) ? bm : bn; \
    const int reg_ = ((u) < 2) ? 0 : 16384; \
    const int rb_ = ((u) & 1) * 128; \
    const uint16_t* g_ = s_ + (size_t)(gb_ + rb_ + (tid >> 2))*KDIM + (kt)*32 + lslot*8; \
    char* d_ = ldsc + (bufb) + reg_ + rb_*64 + w*1024; \
    __builtin_amdgcn_global_load_lds((const __attribute__((address_space(1))) void*)g_, \
                                     (__attribute__((address_space(3))) void*)d_, 16, 0, 0); \
  }

  // lane-constant fragment offsets (swizzled): slot = fq ^ ((fr>>1)&3)
  const int slotoff = (fq ^ ((fr >> 1) & 3)) * 16;
  const int aoff0 = (wm*128 + fr)*64 + slotoff;            // + m*1024 (+4096 for m>=4)
  const int boff0 = 16384 + (wn*64 + fr)*64 + slotoff;     // + n*1024

  // prologue: stage tiles 0 and 1
  STAGE_UNIT(0, 0, 0) STAGE_UNIT(0, 0, 1) STAGE_UNIT(0, 0, 2) STAGE_UNIT(0, 0, 3)
  STAGE_UNIT(1, 32768, 0) STAGE_UNIT(1, 32768, 1) STAGE_UNIT(1, 32768, 2) STAGE_UNIT(1, 32768, 3)
  asm volatile("s_waitcnt vmcnt(4)" ::: "memory");   // tile 0 landed; tile 1 in flight
  __builtin_amdgcn_s_barrier();

  int bR = 0;
  for (int t = 0; t < 32; ++t){
    const int bRb = bR * 32768;
    const int bW  = (bR == 0) ? 2 : (bR - 1);   // == (t+2)%3
    const int bWb = bW * 32768;

    // Tile body: no internal barriers. Compiler inserts fine-grained lgkmcnt
    // between ds_read and dependent MFMA; waves de-phase within the tile so
    // one wave's MFMA overlaps another's ds_read on the CU.
    short8 aF[4], bF[4], aG[4];
    #pragma unroll
    for (int m = 0; m < 4; ++m)
      aF[m] = *(const short8*)(ldsc + bRb + aoff0 + m*1024);
    #pragma unroll
    for (int n = 0; n < 4; ++n)
      bF[n] = *(const short8*)(ldsc + bRb + boff0 + n*1024);
    if (t < 30){ STAGE_UNIT(t+2, bWb, 0) STAGE_UNIT(t+2, bWb, 1) }

    #pragma unroll
    for (int m = 0; m < 4; ++m)
      #pragma unroll
      for (int n = 0; n < 4; ++n)
        acc[m][n] = __builtin_amdgcn_mfma_f32_16x16x32_bf16(aF[m], bF[n], acc[m][n], 0, 0, 0);

    #pragma unroll
    for (int m = 0; m < 4; ++m)
      aG[m] = *(const short8*)(ldsc + bRb + aoff0 + 4096 + m*1024);
    if (t < 30){ STAGE_UNIT(t+2, bWb, 2) STAGE_UNIT(t+2, bWb, 3) }

    #pragma unroll
    for (int m = 0; m < 4; ++m)
      #pragma unroll
      for (int n = 0; n < 4; ++n)
        acc[4+m][n] = __builtin_amdgcn_mfma_f32_16x16x32_bf16(aG[m], bF[n], acc[4+m][n], 0, 0, 0);

    // tile boundary: ensure tile t+1 landed (counted wait, never 0 mid-loop),
    // then one barrier. The asm memory clobber also fences ds_read motion.
    if (t < 30){
      asm volatile("s_waitcnt vmcnt(4)" ::: "memory");
      __builtin_amdgcn_s_barrier();
    } else if (t == 30){
      asm volatile("s_waitcnt vmcnt(0)" ::: "memory");
      __builtin_amdgcn_s_barrier();
    }

    bR = (bR == 2) ? 0 : (bR + 1);
  }
  #undef STAGE_UNIT

  // epilogue: C/D col=lane&15, row=(lane>>4)*4+j; frag pair (2p,2p+1) = (a,v).
  // p innermost so both halves of each 128B av line are written back-to-back.
  const int ebase = (bn + wn*64) >> 1;
  const float bvn0 = bv[ebase + fr];
  const float bvn1 = bv[ebase + 16 + fr];
  #pragma unroll
  for (int m = 0; m < 8; ++m){
    #pragma unroll
    for (int j = 0; j < 4; ++j){
      const int row = bm + wm*128 + m*16 + fq*4 + j;
      const int tt = row >> 5, b = row & 31;
      const size_t base = (size_t)tt*SS + (size_t)b*DD;
      const float a0  = acc[m][0][j];
      const float vt0 = tanh_fast(acc[m][1][j] + bvn0);
      av[base + ebase + fr] = (uint32_t)f2bf(a0) | ((uint32_t)f2bf(vt0) << 16);
      const float a1  = acc[m][2][j];
      const float vt1 = tanh_fast(acc[m][3][j] + bvn1);
      av[base + ebase + 16 + fr] = (uint32_t)f2bf(a1) | ((uint32_t)f2bf(vt1) << 16);
    }
  }
}

// ---------------- scan over t: one thread per (b,e), depth-32 prefetch ----------------
#define SCAN_STEP(u, tcur)                                        \
  {                                                               \
    const float a_ = bf2f((uint16_t)(u));                         \
    const float v_ = bf2f((uint16_t)((u) >> 16));                 \
    const float al_ = sigmoid_fast(a_ + da*h + ba);               \
    h = al_*(h - v_) + v_;                                        \
    const float sg_ = sigmoid_fast(h);                            \
    __builtin_nontemporal_store(h*h*sg_, &outs[(size_t)(tcur)*SS + idx]); \
    __builtin_nontemporal_store(h, &houts[(size_t)((tcur)+1)*SS + idx]);  \
  }

__global__ __launch_bounds__(64) void scan_kernel(const uint32_t* __restrict__ av,
                                                  const float* __restrict__ h0,
                                                  const float* __restrict__ d_alpha,
                                                  const float* __restrict__ b_alpha,
                                                  float* __restrict__ outs,
                                                  float* __restrict__ houts){
  const int idx = blockIdx.x * 64 + threadIdx.x;   // 0..32767 = b*D+e
  const int e = idx & (DD-1);
  const float da = d_alpha[e];
  const float ba = b_alpha[e];
  float h = h0[idx];
  __builtin_nontemporal_store(h, &houts[idx]);

  uint32_t bufA[32], bufB[32];
  #pragma unroll
  for (int j = 0; j < 32; ++j) bufA[j] = av[(size_t)j*SS + idx];

  for (int t0 = 0; t0 < TT; t0 += 64){
    #pragma unroll
    for (int j = 0; j < 32; ++j) bufB[j] = av[(size_t)(t0+32+j)*SS + idx];
    #pragma unroll
    for (int j = 0; j < 32; ++j) SCAN_STEP(bufA[j], t0 + j);
    if (t0 + 64 < TT){
      #pragma unroll
      for (int j = 0; j < 32; ++j) bufA[j] = av[(size_t)(t0+64+j)*SS + idx];
    }
    #pragma unroll
    for (int j = 0; j < 32; ++j) SCAN_STEP(bufB[j], t0 + 32 + j);
  }
}

extern "C" void kernel_launch(void* const* d_in, const int* in_sizes, int n_in,
                              void* d_out, int out_size, void* d_ws, size_t ws_size,
                              hipStream_t stream){
  const float* x  = (const float*)d_in[0];
  const float* h0 = (const float*)d_in[1];
  const float* Wa = (const float*)d_in[2];
  const float* da = (const float*)d_in[3];
  const float* ba = (const float*)d_in[4];
  const float* Wx = (const float*)d_in[5];
  const float* bv = (const float*)d_in[6];

  float* outs  = (float*)d_out;                       // [T,B,D]
  float* houts = outs + (size_t)TT*BB*DD;             // [T+1,B,D]

  // workspace: wc 4MB | xb 64MB | av 128MB
  uint8_t* ws = (uint8_t*)d_ws;
  uint16_t* wcb = (uint16_t*)ws;
  uint16_t* xb  = (uint16_t*)(ws + (size_t)NCOLS*KDIM*2);
  uint32_t* av  = (uint32_t*)(ws + (size_t)NCOLS*KDIM*2 + (size_t)MROWS*KDIM*2);

  hipLaunchKernelGGL(cvt_all_kernel, dim3(2048), dim3(256), 0, stream, Wa, Wx, wcb, x, xb);
  hipLaunchKernelGGL(gemm_dual, dim3((NCOLS/256)*(MROWS/256)), dim3(512), 0, stream,
                     xb, wcb, bv, av);
  hipLaunchKernelGGL(scan_kernel, dim3(SS/64), dim3(64), 0, stream,
                     av, h0, da, ba, outs, houts);
}